// Round 8
// baseline (544.179 us; speedup 1.0000x reference)
//
#include <hip/hip_runtime.h>
#include <math.h>

#define T_SEQ  2048
#define C_DIM  2048
#define H_NUM  16
#define D_HEAD 128
#define MEM_N  1024
#define S_ALL  3072
#define QKV_N  6144

typedef __attribute__((ext_vector_type(4))) float f32x4;
typedef __attribute__((ext_vector_type(8))) short bf16x8;
typedef __attribute__((ext_vector_type(8))) unsigned short us8;

__device__ __forceinline__ unsigned short f2bf(float f) {
    unsigned int u = __float_as_uint(f);
    u = (u + 0x7fffu + ((u >> 16) & 1u)) >> 16;   // RNE
    return (unsigned short)u;
}

// async global->LDS, 16B per lane; lds ptr must be wave-uniform (HW adds lane*16)
__device__ __forceinline__ void gload_lds16(const void* g, void* l) {
    __builtin_amdgcn_global_load_lds((const __attribute__((address_space(1))) void*)g,
                                     (__attribute__((address_space(3))) void*)l, 16, 0, 0);
}

// ===== fused prep: 4 independent memory-bound transforms, one launch ========
// blocks [0,4096)            : split_x  (x fp32 -> Axh/Axl bf16 hi/lo)
// blocks [4096,7168)         : split_w_t(Wqkv -> WqTh), 96x32 tiles
// blocks [7168,8192)         : split_w_t(Wproj -> WpTh), 32x32 tiles
// blocks [8192,8704)         : split_mem (mem -> memb + memt)
__global__ __launch_bounds__(256, 2)
void prep_kernel(const float* __restrict__ x, unsigned short* __restrict__ Axh,
                 unsigned short* __restrict__ Axl,
                 const float* __restrict__ Wqkv, unsigned short* __restrict__ WqTh,
                 const float* __restrict__ Wproj, unsigned short* __restrict__ WpTh,
                 const float* __restrict__ mem, unsigned short* __restrict__ memb,
                 unsigned short* __restrict__ memt)
{
    __shared__ float tile[64][68];
    const int tid = threadIdx.x;
    const int blk = blockIdx.x;

    if (blk < 4096) {
        // ---- split_x ----
        const size_t base = ((size_t)blk * 256 + tid) * 8;
        const float4 a = *(const float4*)(x + base);
        const float4 b = *(const float4*)(x + base + 4);
        float f[8] = {a.x, a.y, a.z, a.w, b.x, b.y, b.z, b.w};
        unsigned int hp[4], lp[4];
#pragma unroll
        for (int e = 0; e < 4; ++e) {
            const unsigned int u0 = __float_as_uint(f[2 * e]), u1 = __float_as_uint(f[2 * e + 1]);
            const float l0 = f[2 * e]     - __uint_as_float(u0 & 0xFFFF0000u);
            const float l1 = f[2 * e + 1] - __uint_as_float(u1 & 0xFFFF0000u);
            hp[e] = (u0 >> 16) | (u1 & 0xFFFF0000u);
            lp[e] = (__float_as_uint(l0) >> 16) | (__float_as_uint(l1) & 0xFFFF0000u);
        }
        *(uint4*)(Axh + base) = make_uint4(hp[0], hp[1], hp[2], hp[3]);
        *(uint4*)(Axl + base) = make_uint4(lp[0], lp[1], lp[2], lp[3]);
        return;
    }

    if (blk < 8192) {
        // ---- split_w_t (two weight matrices) ----
        const bool big = blk < 7168;
        const int idx = big ? blk - 4096 : blk - 7168;
        const int ncols = big ? 96 : 32;
        const int N = big ? QKV_N : C_DIM;
        const float* W = big ? Wqkv : Wproj;
        unsigned short* Th = big ? WqTh : WpTh;
        const int n0 = (idx % ncols) << 6, k0 = (idx / ncols) << 6;
        const int r = tid >> 2, c4 = (tid & 3) << 4;
        const float* src = W + (size_t)(k0 + r) * N + n0 + c4;
#pragma unroll
        for (int i = 0; i < 4; ++i)
            *(float4*)&tile[r][c4 + (i << 2)] = *(const float4*)(src + (i << 2));
        __syncthreads();
        unsigned int hi[8];
#pragma unroll
        for (int e = 0; e < 8; ++e) {
            const unsigned int h0 = f2bf(tile[c4 + 2 * e][r]);
            const unsigned int h1 = f2bf(tile[c4 + 2 * e + 1][r]);
            hi[e] = h0 | (h1 << 16);
        }
        unsigned short* dh = Th + (size_t)(n0 + r) * 2048 + k0 + c4;
        *(uint4*)dh       = make_uint4(hi[0], hi[1], hi[2], hi[3]);
        *(uint4*)(dh + 8) = make_uint4(hi[4], hi[5], hi[6], hi[7]);
        return;
    }

    // ---- split_mem ----
    {
        const int idx = blk - 8192;                 // 32 x 16
        const int c0 = (idx & 31) << 6, s0 = (idx >> 5) << 6;
        const int r = tid >> 2, c4 = (tid & 3) << 4;
        const float* src = mem + (size_t)(s0 + r) * 2048 + c0 + c4;
        unsigned short* db = memb + (size_t)(s0 + r) * 2048 + c0 + c4;
#pragma unroll
        for (int i = 0; i < 4; ++i) {
            const float4 v = *(const float4*)(src + (i << 2));
            *(float4*)&tile[r][c4 + (i << 2)] = v;
            ushort4 o;
            o.x = f2bf(v.x); o.y = f2bf(v.y); o.z = f2bf(v.z); o.w = f2bf(v.w);
            *(ushort4*)(db + (i << 2)) = o;
        }
        __syncthreads();
        unsigned short* dt = memt + (size_t)(c0 + r) * 1024 + s0 + c4;
#pragma unroll
        for (int i = 0; i < 4; ++i) {
            ushort4 o;
            o.x = f2bf(tile[c4 + (i << 2) + 0][r]);
            o.y = f2bf(tile[c4 + (i << 2) + 1][r]);
            o.z = f2bf(tile[c4 + (i << 2) + 2][r]);
            o.w = f2bf(tile[c4 + (i << 2) + 3][r]);
            *(ushort4*)(dt + (i << 2)) = o;
        }
    }
}

// ===== Vr [b,h,2048,128] bf16 -> Vrt [b,h,128,2048] bf16 =====
__global__ __launch_bounds__(256, 2)
void transpose_v_kernel(const unsigned short* __restrict__ Vr, unsigned short* __restrict__ Vrt)
{
    __shared__ unsigned short Vtmp[64 * 136];
    const int tid = threadIdx.x;
    const int s0 = (int)blockIdx.x << 6;
    const int h = blockIdx.y, b = blockIdx.z;
    const size_t bho = (size_t)(b * H_NUM + h) * (2048 * 128);
    const int sr = tid >> 2, ch = (tid & 3) << 5;
    const unsigned short* vp = Vr + bho + (size_t)(s0 + sr) * 128 + ch;
#pragma unroll
    for (int i = 0; i < 4; ++i)
        *(float4*)&Vtmp[sr * 136 + ch + (i << 3)] = *(const float4*)(vp + (i << 3));
    __syncthreads();
    const int d = tid >> 1, half = tid & 1;
    unsigned short* vd = Vrt + bho + (size_t)d * 2048 + s0 + (half << 5);
#pragma unroll
    for (int c = 0; c < 4; ++c) {
        us8 o;
#pragma unroll
        for (int j = 0; j < 8; ++j)
            o[j] = Vtmp[((half << 5) + (c << 3) + j) * 136 + d];
        *(us8*)(vd + (c << 3)) = o;
    }
}

// ===== GEMM1: qkv = [Axh+Axl] @ WqT^T + b; 128x256 block, 64x128/wave ======
// R6 + T1 XCD co-location: grid (24,32), lin%8 = XCD (dispatch round-robin);
// each XCD gets a 3-column x 32-row strip -> per-XCD B working set 3MB
// (L2-resident) instead of every bn-panel bouncing through all 8 L2s.
__global__ __launch_bounds__(256, 2)
void gemm_qkv_mfma(const unsigned short* __restrict__ Axh,
                   const unsigned short* __restrict__ Axl,
                   const unsigned short* __restrict__ Bth,
                   const float* __restrict__ bias,
                   unsigned short* __restrict__ qb, unsigned short* __restrict__ Kr,
                   unsigned short* __restrict__ Vr)
{
    __shared__ unsigned short lds[2][16384];  // per buf: Ah[0:4096] Al[4096:8192] B[8192:16384] (u16)
    const int tid = threadIdx.x;
    const int w = tid >> 6, lane = tid & 63, c16 = lane & 15, quad = lane >> 4;
    const int wm = w & 1, wn = w >> 1;        // wave = rows wm*64, cols wn*128

    // T1: bijective XCD remap (768 blocks, 768%8==0)
    const int lin = (int)blockIdx.x + (int)blockIdx.y * 24;
    const int xcd = lin & 7, idx = lin >> 3;   // idx in [0,96)
    const int bxx = xcd * 3 + (idx >> 5);      // 3 cols per XCD
    const int byy = idx & 31;
    const int bm = byy << 7, bn = bxx << 8;
    const int wofs = w << 10;

    f32x4 acc[32];                            // [mt*8+nt]
#pragma unroll
    for (int i = 0; i < 32; ++i) acc[i] = (f32x4){0.f, 0.f, 0.f, 0.f};

#define STAGE_QKV(buf, kt)                                                        \
    do {                                                                          \
        _Pragma("unroll") for (int j = 0; j < 2; ++j) {                           \
            const int o = (j << 8) + tid;                                         \
            const int r = o >> 2, cc = (o & 3) << 3;                              \
            gload_lds16(Axh + (size_t)(bm + r) * 2048 + (kt) + cc,                \
                        (char*)lds[buf] + (j << 12) + wofs);                      \
            gload_lds16(Axl + (size_t)(bm + r) * 2048 + (kt) + cc,                \
                        (char*)lds[buf] + 8192 + (j << 12) + wofs);               \
        }                                                                         \
        _Pragma("unroll") for (int j = 0; j < 4; ++j) {                           \
            const int o = (j << 8) + tid;                                         \
            const int r = o >> 2, cc = (o & 3) << 3;                              \
            gload_lds16(Bth + (size_t)(bn + r) * 2048 + (kt) + cc,                \
                        (char*)lds[buf] + 16384 + (j << 12) + wofs);              \
        }                                                                         \
    } while (0)

    STAGE_QKV(0, 0);
    __syncthreads();   // drains prologue DMA

    for (int t = 0; t < 64; ++t) {
        const int cur = t & 1;
        if (t + 1 < 64) STAGE_QKV(cur ^ 1, (t + 1) << 5);

        const unsigned short* Ah = lds[cur];
        const unsigned short* Al = Ah + 4096;
        const unsigned short* Bh = Ah + 8192;
        bf16x8 a_h[4], a_l[4];
#pragma unroll
        for (int mt = 0; mt < 4; ++mt) {
            const int ao = (wm * 64 + mt * 16 + c16) * 32 + quad * 8;
            a_h[mt] = *(const bf16x8*)&Ah[ao];
            a_l[mt] = *(const bf16x8*)&Al[ao];
        }
        __builtin_amdgcn_s_setprio(1);
#pragma unroll
        for (int nt = 0; nt < 8; ++nt) {
            const int bo = (wn * 128 + nt * 16 + c16) * 32 + quad * 8;
            const bf16x8 b_h = *(const bf16x8*)&Bh[bo];
#pragma unroll
            for (int mt = 0; mt < 4; ++mt) {
                acc[mt * 8 + nt] = __builtin_amdgcn_mfma_f32_16x16x32_bf16(a_h[mt], b_h, acc[mt * 8 + nt], 0, 0, 0);
                acc[mt * 8 + nt] = __builtin_amdgcn_mfma_f32_16x16x32_bf16(a_l[mt], b_h, acc[mt * 8 + nt], 0, 0, 0);
            }
        }
        __builtin_amdgcn_s_setprio(0);
        __syncthreads();   // drains STAGE(t+1); syncs reads of buf cur
    }

    const int cls = bn >> 11;                 // uniform per block (256 | 2048)
    const float scl = (cls == 0) ? 0.08838834764831845f : 1.0f;
    float bv[8];
#pragma unroll
    for (int nt = 0; nt < 8; ++nt) bv[nt] = bias[bn + wn * 128 + nt * 16 + c16];
#pragma unroll
    for (int mt = 0; mt < 4; ++mt) {
#pragma unroll
        for (int r = 0; r < 4; ++r) {
            const int rg = bm + wm * 64 + mt * 16 + quad * 4 + r;
            if (cls == 0) {
                unsigned short* dst = qb + (size_t)rg * 2048 + bn + wn * 128;
#pragma unroll
                for (int nt = 0; nt < 8; ++nt)
                    dst[nt * 16 + c16] = f2bf((acc[mt * 8 + nt][r] + bv[nt]) * scl);
            } else {
                const int bb = rg >> 11, tt = rg & 2047;
                unsigned short* base = (cls == 1 ? Kr : Vr) + (size_t)(bb * H_NUM) * (2048 * 128) + (size_t)tt * 128;
#pragma unroll
                for (int nt = 0; nt < 8; ++nt) {
                    const int c = (bn & 2047) + wn * 128 + nt * 16 + c16;  // col within class
                    const int hh = c >> 7, d = c & 127;
                    base[(size_t)hh * (2048 * 128) + d] = f2bf(acc[mt * 8 + nt][r] + bv[nt]);
                }
            }
        }
    }
}

// ===== GEMM2: out = (attn_h+attn_l) @ WpT^T + b; T3-min pipeline + T1 =====
__global__ __launch_bounds__(256, 3)
void gemm_proj_mfma(const unsigned short* __restrict__ Ahg, const unsigned short* __restrict__ Alg,
                    const unsigned short* __restrict__ Bth,
                    const float* __restrict__ bias, float* __restrict__ out)
{
    __shared__ unsigned short lds[6][4096];   // 48 KB
    const int tid = threadIdx.x;
    const int w = tid >> 6, lane = tid & 63, c16 = lane & 15, quad = lane >> 4;
    const int wm = w & 1, wn = w >> 1;

    // T1: bijective XCD remap (512 blocks, 512%8==0): 2 cols x 32 rows per XCD
    const int lin = (int)blockIdx.x + (int)blockIdx.y * 16;
    const int xcd = lin & 7, idx = lin >> 3;   // idx in [0,64)
    const int bxx = xcd * 2 + (idx >> 5);
    const int byy = idx & 31;
    const int bm = byy << 7, bn = bxx << 7;
    const int wofs = w << 10;

    f32x4 acc[16];
#pragma unroll
    for (int i = 0; i < 16; ++i) acc[i] = (f32x4){0.f, 0.f, 0.f, 0.f};

#define STAGE_PROJ(buf, kt)                                                       \
    do {                                                                          \
        _Pragma("unroll") for (int j = 0; j < 2; ++j) {                           \
            const int o = (j << 8) + tid;                                         \
            const int r = o >> 2, cc = (o & 3) << 3;                              \
            gload_lds16(Ahg + (size_t)(bm + r) * 2048 + (kt) + cc,                \
                        (char*)&lds[(buf) * 3 + 0][0] + (j << 12) + wofs);        \
            gload_lds16(Alg + (size_t)(bm + r) * 2048 + (kt) + cc,                \
                        (char*)&lds[(buf) * 3 + 1][0] + (j << 12) + wofs);        \
            gload_lds16(Bth + (size_t)(bn + r) * 2048 + (kt) + cc,                \
                        (char*)&lds[(buf) * 3 + 2][0] + (j << 12) + wofs);        \
        }                                                                         \
    } while (0)

    STAGE_PROJ(0, 0);
    __syncthreads();

    for (int t = 0; t < 64; ++t) {
        const int cur = t & 1;
        if (t + 1 < 64) STAGE_PROJ(cur ^ 1, (t + 1) << 5);

        const unsigned short* Ah = lds[cur * 3 + 0];
        const unsigned short* Al = lds[cur * 3 + 1];
        const unsigned short* Bh = lds[cur * 3 + 2];
        bf16x8 a_h[4], a_l[4];
#pragma unroll
        for (int mt = 0; mt < 4; ++mt) {
            const int ao = (wm * 64 + mt * 16 + c16) * 32 + quad * 8;
            a_h[mt] = *(const bf16x8*)&Ah[ao];
            a_l[mt] = *(const bf16x8*)&Al[ao];
        }
        __builtin_amdgcn_s_setprio(1);
#pragma unroll
        for (int nt = 0; nt < 4; ++nt) {
            const int bo = (wn * 64 + nt * 16 + c16) * 32 + quad * 8;
            const bf16x8 b_h = *(const bf16x8*)&Bh[bo];
#pragma unroll
            for (int mt = 0; mt < 4; ++mt) {
                acc[mt * 4 + nt] = __builtin_amdgcn_mfma_f32_16x16x32_bf16(a_h[mt], b_h, acc[mt * 4 + nt], 0, 0, 0);
                acc[mt * 4 + nt] = __builtin_amdgcn_mfma_f32_16x16x32_bf16(a_l[mt], b_h, acc[mt * 4 + nt], 0, 0, 0);
            }
        }
        __builtin_amdgcn_s_setprio(0);
        __syncthreads();
    }

    float bv[4];
#pragma unroll
    for (int nt = 0; nt < 4; ++nt) bv[nt] = bias[bn + wn * 64 + nt * 16 + c16];
#pragma unroll
    for (int mt = 0; mt < 4; ++mt) {
#pragma unroll
        for (int r = 0; r < 4; ++r) {
            const int rg = bm + wm * 64 + mt * 16 + quad * 4 + r;
            float* dst = out + (size_t)rg * 2048 + bn + wn * 64 + c16;
#pragma unroll
            for (int nt = 0; nt < 4; ++nt)
                dst[nt * 16] = acc[mt * 4 + nt][r] + bv[nt];
        }
    }
}

// ---- DMA staging with XOR-swizzle via pre-swizzled GLOBAL source (m173/m201)
__device__ __forceinline__ void stage_k(const unsigned short* __restrict__ kb, int kst,
                                        unsigned short* KsX, int w, int lane)
{
#pragma unroll
    for (int i = 0; i < 4; ++i) {
        const int o = (w << 12) + (i << 10) + (lane << 4);   // byte offset in 16KB tile
        const int r = o >> 8;
        const int c = ((o >> 4) & 15) ^ (r & 7);
        gload_lds16(kb + (size_t)r * kst + (c << 3), (char*)KsX + (w << 12) + (i << 10));
    }
}
__device__ __forceinline__ void stage_v(const unsigned short* __restrict__ vb, int vst,
                                        unsigned short* VsX, int w, int lane)
{
#pragma unroll
    for (int i = 0; i < 4; ++i) {
        const int o = (w << 12) + (i << 10) + (lane << 4);
        const int r = o >> 7;
        const int c = ((o >> 4) & 7) ^ (r & 7);
        gload_lds16(vb + (size_t)r * vst + (c << 3), (char*)VsX + (w << 12) + (i << 10));
    }
}

// ============ MFMA flash attention — DMA-staged, swizzled, spill-free ======
// (unchanged from round 4/6 — control this round)
__global__ __launch_bounds__(256, 2)
void attn_mfma_kernel(const unsigned short* __restrict__ qb,
                      const unsigned short* __restrict__ Kr,
                      const unsigned short* __restrict__ memb,
                      const unsigned short* __restrict__ Vrt,
                      const unsigned short* __restrict__ memt,
                      unsigned short* __restrict__ attn_h,
                      unsigned short* __restrict__ attn_l)
{
    __shared__ unsigned short lds[40960];     // 81,920 B
    unsigned short* Ks0 = lds;                // 16 KB each
    unsigned short* Ks1 = lds + 8192;
    unsigned short* Vs0 = lds + 16384;
    unsigned short* Vs1 = lds + 24576;
    unsigned short* Ps  = lds + 32768;        // 128 x 64 u16, swizzled
    unsigned short* Os  = lds;                // overlay: Q stage / epilogue (34,816 B)

    const int tid = threadIdx.x;
    const int w = tid >> 6, lane = tid & 63;
    const int c16 = lane & 15, quad = lane >> 4;
    const int bx = blockIdx.x;
    const int h = blockIdx.y, b = blockIdx.z;
    const int qt = b ? bx : (15 - bx);
    const int t0 = qt << 7;               // 128-row q tile
    const int bT = b * T_SEQ;
    const int bh = b * H_NUM + h;

    const unsigned short* Krb = Kr + (size_t)bh * (2048 * 128);
    const unsigned short* Vrb = Vrt + (size_t)bh * (2048 * 128);
    const unsigned short* membh = memb + h * D_HEAD;
    const unsigned short* memth = memt + (size_t)h * D_HEAD * 1024;

    bf16x8 qfrag[2][4];
    {
        const int row = tid >> 1, co = (tid & 1) << 6;
        const unsigned short* src = qb + (size_t)(bT + t0 + row) * 2048 + h * D_HEAD + co;
#pragma unroll
        for (int i = 0; i < 8; ++i)
            *(float4*)&Os[row * 136 + co + (i << 3)] = *(const float4*)(src + (i << 3));
#pragma unroll
        for (int qi = 0; qi < 2; ++qi) {
            const int q = (w << 5) + qi * 16 + c16;
#pragma unroll
            for (int kk = 0; kk < 4; ++kk)
                qfrag[qi][kk] = *(const bf16x8*)&Os[q * 136 + (kk << 5) + (quad << 3)];
        }
    }
    __syncthreads();   // all Q frags read before DMA overwrites the overlay

    f32x4 acc_o[2][8];
#pragma unroll
    for (int qi = 0; qi < 2; ++qi)
#pragma unroll
        for (int i = 0; i < 8; ++i) acc_o[qi][i] = (f32x4){0.f, 0.f, 0.f, 0.f};
    float m_r[2] = {-1e30f, -1e30f};
    float l_r[2] = {0.f, 0.f};

    const int nk = (t0 >> 6) + 2;          // causal s-tiles (64 wide)
    const int ntile = nk + (MEM_N >> 6);

    stage_k(Krb, 128, Ks0, w, lane);
    stage_v(Vrb, 2048, Vs0, w, lane);

    const int sw = c16 & 7;                // read-side XOR key (row & 7)

    for (int it = 0; it < ntile; ++it) {
        __syncthreads();   // drains vmcnt: tile[it] staged; prev compute done

        if (it + 1 < ntile) {
            const int nx = it + 1;
            const bool nm = nx >= nk;
            const int sl = (nm ? nx - nk : nx) << 6;
            const unsigned short* kb = nm ? membh + (size_t)sl * 2048 : Krb + (size_t)sl * 128;
            const unsigned short* vb = nm ? memth + sl : Vrb + sl;
            stage_k(kb, nm ? 2048 : 128, (it & 1) ? Ks0 : Ks1, w, lane);
            stage_v(vb, nm ? 1024 : 2048, (it & 1) ? Vs0 : Vs1, w, lane);
        }

        const unsigned short* Kc = (it & 1) ? Ks1 : Ks0;
        const unsigned short* Vc = (it & 1) ? Vs1 : Vs0;
        const bool mem_t = it >= nk;
        const int sl0 = (mem_t ? it - nk : it) << 6;
        const int s0 = mem_t ? T_SEQ + sl0 : sl0;

        const bool active = mem_t || (s0 <= t0 + (w << 5) + 31);
        if (active) {
            f32x4 acc_s[4][2];
#pragma unroll
            for (int nt = 0; nt < 4; ++nt)
#pragma unroll
                for (int qi = 0; qi < 2; ++qi) acc_s[nt][qi] = (f32x4){0.f, 0.f, 0.f, 0.f};

            bf16x8 ka[4][4];
#pragma unroll
            for (int nt = 0; nt < 4; ++nt) {
                const int rr = nt * 16 + c16;
#pragma unroll
                for (int kk = 0; kk < 4; ++kk)
                    ka[nt][kk] = *(const bf16x8*)&Kc[rr * 128 + ((((kk << 2) + quad) ^ sw) << 3)];
            }
            __builtin_amdgcn_s_setprio(1);
#pragma unroll
            for (int kk = 0; kk < 4; ++kk)
#pragma unroll
                for (int nt = 0; nt < 4; ++nt)
#pragma unroll
                    for (int qi = 0; qi < 2; ++qi)
                        acc_s[nt][qi] = __builtin_amdgcn_mfma_f32_16x16x32_bf16(ka[nt][kk], qfrag[qi][kk], acc_s[nt][qi], 0, 0, 0);
            __builtin_amdgcn_s_setprio(0);

            if (!mem_t && (s0 + 63 > t0 + (w << 5))) {
#pragma unroll
                for (int nt = 0; nt < 4; ++nt) {
                    const int sbase = s0 + nt * 16 + quad * 4;
#pragma unroll
                    for (int qi = 0; qi < 2; ++qi) {
                        const int q = t0 + (w << 5) + qi * 16 + c16;
#pragma unroll
                        for (int r = 0; r < 4; ++r)
                            if (sbase + r > q) acc_s[nt][qi][r] = -1e30f;
                    }
                }
            }

            float mx[2], al[2], rs[2];
#pragma unroll
            for (int qi = 0; qi < 2; ++qi) {
                float m0 = fmaxf(fmaxf(acc_s[0][qi][0], acc_s[0][qi][1]), fmaxf(acc_s[0][qi][2], acc_s[0][qi][3]));
#pragma unroll
                for (int nt = 1; nt < 4; ++nt)
                    m0 = fmaxf(m0, fmaxf(fmaxf(acc_s[nt][qi][0], acc_s[nt][qi][1]), fmaxf(acc_s[nt][qi][2], acc_s[nt][qi][3])));
                m0 = fmaxf(m0, __shfl_xor(m0, 16));
                m0 = fmaxf(m0, __shfl_xor(m0, 32));
                mx[qi] = m0;
            }
#pragma unroll
            for (int qi = 0; qi < 2; ++qi) {
                const float mn = fmaxf(m_r[qi], mx[qi]);
                al[qi] = __expf(m_r[qi] - mn);
                m_r[qi] = mn;
                float s = 0.f;
#pragma unroll
                for (int nt = 0; nt < 4; ++nt)
#pragma unroll
                    for (int r = 0; r < 4; ++r) {
                        const float p = __expf(acc_s[nt][qi][r] - mn);
                        acc_s[nt][qi][r] = p;
                        s += p;
                    }
                rs[qi] = s;
            }
#pragma unroll
            for (int qi = 0; qi < 2; ++qi) {
                rs[qi] += __shfl_xor(rs[qi], 16);
                rs[qi] += __shfl_xor(rs[qi], 32);
                l_r[qi] = l_r[qi] * al[qi] + rs[qi];
#pragma unroll
                for (int dt = 0; dt < 8; ++dt)
#pragma unroll
                    for (int r = 0; r < 4; ++r) acc_o[qi][dt][r] *= al[qi];
            }

#pragma unroll
            for (int qi = 0; qi < 2; ++qi) {
                const int q = (w << 5) + qi * 16 + c16;
                const int qx = (q & 7) << 4;
#pragma unroll
                for (int nt = 0; nt < 4; ++nt) {
                    ushort4 pk;
                    pk.x = f2bf(acc_s[nt][qi][0]); pk.y = f2bf(acc_s[nt][qi][1]);
                    pk.z = f2bf(acc_s[nt][qi][2]); pk.w = f2bf(acc_s[nt][qi][3]);
                    *(ushort4*)((char*)Ps + q * 128 + (((nt << 5) + (quad << 3)) ^ qx)) = pk;
                }
            }

            __builtin_amdgcn_s_setprio(1);
#pragma unroll
            for (int ks = 0; ks < 2; ++ks) {
                bf16x8 pb[2];
#pragma unroll
                for (int qi = 0; qi < 2; ++qi) {
                    const int q = (w << 5) + qi * 16 + c16;
                    pb[qi] = *(const bf16x8*)((char*)Ps + q * 128 + (((ks << 6) + (quad << 4)) ^ ((q & 7) << 4)));
                }
#pragma unroll
                for (int dt = 0; dt < 8; ++dt) {
                    const int rr = dt * 16 + c16;
                    const bf16x8 va = *(const bf16x8*)&Vc[rr * 64 + ((((ks << 2) + quad) ^ sw) << 3)];
                    acc_o[0][dt] = __builtin_amdgcn_mfma_f32_16x16x32_bf16(va, pb[0], acc_o[0][dt], 0, 0, 0);
                    acc_o[1][dt] = __builtin_amdgcn_mfma_f32_16x16x32_bf16(va, pb[1], acc_o[1][dt], 0, 0, 0);
                }
            }
            __builtin_amdgcn_s_setprio(0);
        }
    }

    __syncthreads();   // all compute done; Os overlays the K/V buffers
    const float inv[2] = {1.0f / l_r[0], 1.0f / l_r[1]};
    const int row = tid >> 1, co = (tid & 1) << 6;
    unsigned short* gh = attn_h + (size_t)(bT + t0 + row) * 2048 + h * D_HEAD + co;
    unsigned short* gl = attn_l + (size_t)(bT + t0 + row) * 2048 + h * D_HEAD + co;

#pragma unroll
    for (int pass = 0; pass < 2; ++pass) {
#pragma unroll
        for (int qi = 0; qi < 2; ++qi) {
            const int q = (w << 5) + qi * 16 + c16;
#pragma unroll
            for (int dt = 0; dt < 8; ++dt) {
                ushort4 ov;
                unsigned short* po = (unsigned short*)&ov;
#pragma unroll
                for (int r = 0; r < 4; ++r) {
                    const float o = acc_o[qi][dt][r] * inv[qi];
                    const unsigned int u = __float_as_uint(o);
                    if (pass == 0) {
                        po[r] = (unsigned short)(u >> 16);     // truncated hi
                    } else {
                        const float lo = o - __uint_as_float(u & 0xFFFF0000u);
                        po[r] = f2bf(lo);
                    }
                }
                *(ushort4*)&Os[q * 136 + dt * 16 + quad * 4] = ov;
            }
        }
        unsigned short* g = (pass == 0) ? gh : gl;
#pragma unroll
        for (int i = 0; i < 8; ++i)
            *(float4*)(g + (i << 3)) = *(const float4*)&Os[row * 136 + co + (i << 3)];
    }
}

extern "C" void kernel_launch(void* const* d_in, const int* in_sizes, int n_in,
                              void* d_out, int out_size, void* d_ws, size_t ws_size,
                              hipStream_t stream)
{
    const float* x     = (const float*)d_in[0];
    const float* Wqkv  = (const float*)d_in[1];
    const float* bqkv  = (const float*)d_in[2];
    const float* mem   = (const float*)d_in[3];
    const float* Wproj = (const float*)d_in[4];
    const float* bproj = (const float*)d_in[5];
    float* out = (float*)d_out;

    unsigned short* ws16 = (unsigned short*)d_ws;
    unsigned short* WqTh = ws16;                         // 12,582,912
    unsigned short* rgn2 = WqTh + 12582912;              // 12,582,912
    unsigned short* qb   = rgn2 + 12582912;              //  8,388,608
    unsigned short* Kr   = qb   + 8388608;               //  8,388,608
    unsigned short* Vr   = Kr   + 8388608;               //  8,388,608
    unsigned short* Vrt  = Vr   + 8388608;               //  8,388,608
    unsigned short* memb = Vrt  + 8388608;               //  2,097,152
    unsigned short* memt = memb + 2097152;               //  2,097,152
    unsigned short* attn_h = WqTh;                       // overlay (WqTh dead after gemm1)
    unsigned short* attn_l = rgn2;
    unsigned short* WpTh = rgn2 + 8388608;               //  4,194,304 tail
    unsigned short* Axh = rgn2;                          // dead before attn_l is written
    unsigned short* Axl = Vrt;                           // dead before transpose_v writes Vrt

    prep_kernel<<<dim3(8704), 256, 0, stream>>>(x, Axh, Axl, Wqkv, WqTh,
                                                Wproj, WpTh, mem, memb, memt);

    gemm_qkv_mfma<<<dim3(24, 32), 256, 0, stream>>>(Axh, Axl, WqTh, bqkv, qb, Kr, Vr);

    transpose_v_kernel<<<dim3(32, 16, 2), 256, 0, stream>>>(Vr, Vrt);

    attn_mfma_kernel<<<dim3(16, 16, 2), 256, 0, stream>>>(qb, Kr, memb, Vrt, memt, attn_h, attn_l);

    gemm_proj_mfma<<<dim3(16, 32), 256, 0, stream>>>(attn_h, attn_l, WpTh, bproj, out);
}

// Round 9
// 525.403 us; speedup vs baseline: 1.0357x; 1.0357x over previous
//
#include <hip/hip_runtime.h>
#include <math.h>

#define T_SEQ  2048
#define C_DIM  2048
#define H_NUM  16
#define D_HEAD 128
#define MEM_N  1024
#define S_ALL  3072
#define QKV_N  6144

typedef __attribute__((ext_vector_type(4))) float f32x4;
typedef __attribute__((ext_vector_type(8))) short bf16x8;
typedef __attribute__((ext_vector_type(8))) unsigned short us8;

__device__ __forceinline__ unsigned short f2bf(float f) {
    unsigned int u = __float_as_uint(f);
    u = (u + 0x7fffu + ((u >> 16) & 1u)) >> 16;   // RNE
    return (unsigned short)u;
}

// async global->LDS, 16B per lane; lds ptr must be wave-uniform (HW adds lane*16)
__device__ __forceinline__ void gload_lds16(const void* g, void* l) {
    __builtin_amdgcn_global_load_lds((const __attribute__((address_space(1))) void*)g,
                                     (__attribute__((address_space(3))) void*)l, 16, 0, 0);
}

// ===== fused prep: 4 independent memory-bound transforms, one launch ========
__global__ __launch_bounds__(256, 2)
void prep_kernel(const float* __restrict__ x, unsigned short* __restrict__ Axh,
                 unsigned short* __restrict__ Axl,
                 const float* __restrict__ Wqkv, unsigned short* __restrict__ WqTh,
                 const float* __restrict__ Wproj, unsigned short* __restrict__ WpTh,
                 const float* __restrict__ mem, unsigned short* __restrict__ memb,
                 unsigned short* __restrict__ memt)
{
    __shared__ float tile[64][68];
    const int tid = threadIdx.x;
    const int blk = blockIdx.x;

    if (blk < 4096) {
        // ---- split_x ----
        const size_t base = ((size_t)blk * 256 + tid) * 8;
        const float4 a = *(const float4*)(x + base);
        const float4 b = *(const float4*)(x + base + 4);
        float f[8] = {a.x, a.y, a.z, a.w, b.x, b.y, b.z, b.w};
        unsigned int hp[4], lp[4];
#pragma unroll
        for (int e = 0; e < 4; ++e) {
            const unsigned int u0 = __float_as_uint(f[2 * e]), u1 = __float_as_uint(f[2 * e + 1]);
            const float l0 = f[2 * e]     - __uint_as_float(u0 & 0xFFFF0000u);
            const float l1 = f[2 * e + 1] - __uint_as_float(u1 & 0xFFFF0000u);
            hp[e] = (u0 >> 16) | (u1 & 0xFFFF0000u);
            lp[e] = (__float_as_uint(l0) >> 16) | (__float_as_uint(l1) & 0xFFFF0000u);
        }
        *(uint4*)(Axh + base) = make_uint4(hp[0], hp[1], hp[2], hp[3]);
        *(uint4*)(Axl + base) = make_uint4(lp[0], lp[1], lp[2], lp[3]);
        return;
    }

    if (blk < 8192) {
        // ---- split_w_t (two weight matrices) ----
        const bool big = blk < 7168;
        const int idx = big ? blk - 4096 : blk - 7168;
        const int ncols = big ? 96 : 32;
        const int N = big ? QKV_N : C_DIM;
        const float* W = big ? Wqkv : Wproj;
        unsigned short* Th = big ? WqTh : WpTh;
        const int n0 = (idx % ncols) << 6, k0 = (idx / ncols) << 6;
        const int r = tid >> 2, c4 = (tid & 3) << 4;
        const float* src = W + (size_t)(k0 + r) * N + n0 + c4;
#pragma unroll
        for (int i = 0; i < 4; ++i)
            *(float4*)&tile[r][c4 + (i << 2)] = *(const float4*)(src + (i << 2));
        __syncthreads();
        unsigned int hi[8];
#pragma unroll
        for (int e = 0; e < 8; ++e) {
            const unsigned int h0 = f2bf(tile[c4 + 2 * e][r]);
            const unsigned int h1 = f2bf(tile[c4 + 2 * e + 1][r]);
            hi[e] = h0 | (h1 << 16);
        }
        unsigned short* dh = Th + (size_t)(n0 + r) * 2048 + k0 + c4;
        *(uint4*)dh       = make_uint4(hi[0], hi[1], hi[2], hi[3]);
        *(uint4*)(dh + 8) = make_uint4(hi[4], hi[5], hi[6], hi[7]);
        return;
    }

    // ---- split_mem ----
    {
        const int idx = blk - 8192;                 // 32 x 16
        const int c0 = (idx & 31) << 6, s0 = (idx >> 5) << 6;
        const int r = tid >> 2, c4 = (tid & 3) << 4;
        const float* src = mem + (size_t)(s0 + r) * 2048 + c0 + c4;
        unsigned short* db = memb + (size_t)(s0 + r) * 2048 + c0 + c4;
#pragma unroll
        for (int i = 0; i < 4; ++i) {
            const float4 v = *(const float4*)(src + (i << 2));
            *(float4*)&tile[r][c4 + (i << 2)] = v;
            ushort4 o;
            o.x = f2bf(v.x); o.y = f2bf(v.y); o.z = f2bf(v.z); o.w = f2bf(v.w);
            *(ushort4*)(db + (i << 2)) = o;
        }
        __syncthreads();
        unsigned short* dt = memt + (size_t)(c0 + r) * 1024 + s0 + c4;
#pragma unroll
        for (int i = 0; i < 4; ++i) {
            ushort4 o;
            o.x = f2bf(tile[c4 + (i << 2) + 0][r]);
            o.y = f2bf(tile[c4 + (i << 2) + 1][r]);
            o.z = f2bf(tile[c4 + (i << 2) + 2][r]);
            o.w = f2bf(tile[c4 + (i << 2) + 3][r]);
            *(ushort4*)(dt + (i << 2)) = o;
        }
    }
}

// ===== Vr [b,h,2048,128] bf16 -> Vrt [b,h,128,2048] bf16 =====
__global__ __launch_bounds__(256, 2)
void transpose_v_kernel(const unsigned short* __restrict__ Vr, unsigned short* __restrict__ Vrt)
{
    __shared__ unsigned short Vtmp[64 * 136];
    const int tid = threadIdx.x;
    const int s0 = (int)blockIdx.x << 6;
    const int h = blockIdx.y, b = blockIdx.z;
    const size_t bho = (size_t)(b * H_NUM + h) * (2048 * 128);
    const int sr = tid >> 2, ch = (tid & 3) << 5;
    const unsigned short* vp = Vr + bho + (size_t)(s0 + sr) * 128 + ch;
#pragma unroll
    for (int i = 0; i < 4; ++i)
        *(float4*)&Vtmp[sr * 136 + ch + (i << 3)] = *(const float4*)(vp + (i << 3));
    __syncthreads();
    const int d = tid >> 1, half = tid & 1;
    unsigned short* vd = Vrt + bho + (size_t)d * 2048 + s0 + (half << 5);
#pragma unroll
    for (int c = 0; c < 4; ++c) {
        us8 o;
#pragma unroll
        for (int j = 0; j < 8; ++j)
            o[j] = Vtmp[((half << 5) + (c << 3) + j) * 136 + d];
        *(us8*)(vd + (c << 3)) = o;
    }
}

// ===== GEMM1: qkv = [Axh+Axl] @ WqT^T + b; 128x256 block, 64x128/wave ======
// R8 post-mortem: XCD remap REVERTED — it optimized B-panel residency (1MB)
// but broke A-panel L2 sharing (32MB swept 3x per XCD): FETCH 172->387MB,
// dur +5us. Default x-major dispatch keeps concurrent same-bm blocks sharing
// A panels in L2. (R6-verified: 179us, FETCH 172MB, MfmaUtil 54%.)
__global__ __launch_bounds__(256, 2)
void gemm_qkv_mfma(const unsigned short* __restrict__ Axh,
                   const unsigned short* __restrict__ Axl,
                   const unsigned short* __restrict__ Bth,
                   const float* __restrict__ bias,
                   unsigned short* __restrict__ qb, unsigned short* __restrict__ Kr,
                   unsigned short* __restrict__ Vr)
{
    __shared__ unsigned short lds[2][16384];  // per buf: Ah[0:4096] Al[4096:8192] B[8192:16384] (u16)
    const int tid = threadIdx.x;
    const int w = tid >> 6, lane = tid & 63, c16 = lane & 15, quad = lane >> 4;
    const int wm = w & 1, wn = w >> 1;        // wave = rows wm*64, cols wn*128
    const int bm = blockIdx.y << 7, bn = blockIdx.x << 8;
    const int wofs = w << 10;

    f32x4 acc[32];                            // [mt*8+nt]
#pragma unroll
    for (int i = 0; i < 32; ++i) acc[i] = (f32x4){0.f, 0.f, 0.f, 0.f};

#define STAGE_QKV(buf, kt)                                                        \
    do {                                                                          \
        _Pragma("unroll") for (int j = 0; j < 2; ++j) {                           \
            const int o = (j << 8) + tid;                                         \
            const int r = o >> 2, cc = (o & 3) << 3;                              \
            gload_lds16(Axh + (size_t)(bm + r) * 2048 + (kt) + cc,                \
                        (char*)lds[buf] + (j << 12) + wofs);                      \
            gload_lds16(Axl + (size_t)(bm + r) * 2048 + (kt) + cc,                \
                        (char*)lds[buf] + 8192 + (j << 12) + wofs);               \
        }                                                                         \
        _Pragma("unroll") for (int j = 0; j < 4; ++j) {                           \
            const int o = (j << 8) + tid;                                         \
            const int r = o >> 2, cc = (o & 3) << 3;                              \
            gload_lds16(Bth + (size_t)(bn + r) * 2048 + (kt) + cc,                \
                        (char*)lds[buf] + 16384 + (j << 12) + wofs);              \
        }                                                                         \
    } while (0)

    STAGE_QKV(0, 0);
    __syncthreads();   // drains prologue DMA

    for (int t = 0; t < 64; ++t) {
        const int cur = t & 1;
        if (t + 1 < 64) STAGE_QKV(cur ^ 1, (t + 1) << 5);

        const unsigned short* Ah = lds[cur];
        const unsigned short* Al = Ah + 4096;
        const unsigned short* Bh = Ah + 8192;
        bf16x8 a_h[4], a_l[4];
#pragma unroll
        for (int mt = 0; mt < 4; ++mt) {
            const int ao = (wm * 64 + mt * 16 + c16) * 32 + quad * 8;
            a_h[mt] = *(const bf16x8*)&Ah[ao];
            a_l[mt] = *(const bf16x8*)&Al[ao];
        }
        __builtin_amdgcn_s_setprio(1);
#pragma unroll
        for (int nt = 0; nt < 8; ++nt) {
            const int bo = (wn * 128 + nt * 16 + c16) * 32 + quad * 8;
            const bf16x8 b_h = *(const bf16x8*)&Bh[bo];
#pragma unroll
            for (int mt = 0; mt < 4; ++mt) {
                acc[mt * 8 + nt] = __builtin_amdgcn_mfma_f32_16x16x32_bf16(a_h[mt], b_h, acc[mt * 8 + nt], 0, 0, 0);
                acc[mt * 8 + nt] = __builtin_amdgcn_mfma_f32_16x16x32_bf16(a_l[mt], b_h, acc[mt * 8 + nt], 0, 0, 0);
            }
        }
        __builtin_amdgcn_s_setprio(0);
        __syncthreads();   // drains STAGE(t+1); syncs reads of buf cur
    }

    const int cls = bn >> 11;                 // uniform per block (256 | 2048)
    const float scl = (cls == 0) ? 0.08838834764831845f : 1.0f;
    float bv[8];
#pragma unroll
    for (int nt = 0; nt < 8; ++nt) bv[nt] = bias[bn + wn * 128 + nt * 16 + c16];
#pragma unroll
    for (int mt = 0; mt < 4; ++mt) {
#pragma unroll
        for (int r = 0; r < 4; ++r) {
            const int rg = bm + wm * 64 + mt * 16 + quad * 4 + r;
            if (cls == 0) {
                unsigned short* dst = qb + (size_t)rg * 2048 + bn + wn * 128;
#pragma unroll
                for (int nt = 0; nt < 8; ++nt)
                    dst[nt * 16 + c16] = f2bf((acc[mt * 8 + nt][r] + bv[nt]) * scl);
            } else {
                const int bb = rg >> 11, tt = rg & 2047;
                unsigned short* base = (cls == 1 ? Kr : Vr) + (size_t)(bb * H_NUM) * (2048 * 128) + (size_t)tt * 128;
#pragma unroll
                for (int nt = 0; nt < 8; ++nt) {
                    const int c = (bn & 2047) + wn * 128 + nt * 16 + c16;  // col within class
                    const int hh = c >> 7, d = c & 127;
                    base[(size_t)hh * (2048 * 128) + d] = f2bf(acc[mt * 8 + nt][r] + bv[nt]);
                }
            }
        }
    }
}

// ===== GEMM2: out = (attn_h+attn_l) @ WpT^^T + b; T3-min pipeline (R6 map) ==
__global__ __launch_bounds__(256, 3)
void gemm_proj_mfma(const unsigned short* __restrict__ Ahg, const unsigned short* __restrict__ Alg,
                    const unsigned short* __restrict__ Bth,
                    const float* __restrict__ bias, float* __restrict__ out)
{
    __shared__ unsigned short lds[6][4096];   // 48 KB
    const int tid = threadIdx.x;
    const int w = tid >> 6, lane = tid & 63, c16 = lane & 15, quad = lane >> 4;
    const int wm = w & 1, wn = w >> 1;
    const int bm = blockIdx.y << 7, bn = blockIdx.x << 7;
    const int wofs = w << 10;

    f32x4 acc[16];
#pragma unroll
    for (int i = 0; i < 16; ++i) acc[i] = (f32x4){0.f, 0.f, 0.f, 0.f};

#define STAGE_PROJ(buf, kt)                                                       \
    do {                                                                          \
        _Pragma("unroll") for (int j = 0; j < 2; ++j) {                           \
            const int o = (j << 8) + tid;                                         \
            const int r = o >> 2, cc = (o & 3) << 3;                              \
            gload_lds16(Ahg + (size_t)(bm + r) * 2048 + (kt) + cc,                \
                        (char*)&lds[(buf) * 3 + 0][0] + (j << 12) + wofs);        \
            gload_lds16(Alg + (size_t)(bm + r) * 2048 + (kt) + cc,                \
                        (char*)&lds[(buf) * 3 + 1][0] + (j << 12) + wofs);        \
            gload_lds16(Bth + (size_t)(bn + r) * 2048 + (kt) + cc,                \
                        (char*)&lds[(buf) * 3 + 2][0] + (j << 12) + wofs);        \
        }                                                                         \
    } while (0)

    STAGE_PROJ(0, 0);
    __syncthreads();

    for (int t = 0; t < 64; ++t) {
        const int cur = t & 1;
        if (t + 1 < 64) STAGE_PROJ(cur ^ 1, (t + 1) << 5);

        const unsigned short* Ah = lds[cur * 3 + 0];
        const unsigned short* Al = lds[cur * 3 + 1];
        const unsigned short* Bh = lds[cur * 3 + 2];
        bf16x8 a_h[4], a_l[4];
#pragma unroll
        for (int mt = 0; mt < 4; ++mt) {
            const int ao = (wm * 64 + mt * 16 + c16) * 32 + quad * 8;
            a_h[mt] = *(const bf16x8*)&Ah[ao];
            a_l[mt] = *(const bf16x8*)&Al[ao];
        }
        __builtin_amdgcn_s_setprio(1);
#pragma unroll
        for (int nt = 0; nt < 4; ++nt) {
            const int bo = (wn * 64 + nt * 16 + c16) * 32 + quad * 8;
            const bf16x8 b_h = *(const bf16x8*)&Bh[bo];
#pragma unroll
            for (int mt = 0; mt < 4; ++mt) {
                acc[mt * 4 + nt] = __builtin_amdgcn_mfma_f32_16x16x32_bf16(a_h[mt], b_h, acc[mt * 4 + nt], 0, 0, 0);
                acc[mt * 4 + nt] = __builtin_amdgcn_mfma_f32_16x16x32_bf16(a_l[mt], b_h, acc[mt * 4 + nt], 0, 0, 0);
            }
        }
        __builtin_amdgcn_s_setprio(0);
        __syncthreads();
    }

    float bv[4];
#pragma unroll
    for (int nt = 0; nt < 4; ++nt) bv[nt] = bias[bn + wn * 64 + nt * 16 + c16];
#pragma unroll
    for (int mt = 0; mt < 4; ++mt) {
#pragma unroll
        for (int r = 0; r < 4; ++r) {
            const int rg = bm + wm * 64 + mt * 16 + quad * 4 + r;
            float* dst = out + (size_t)rg * 2048 + bn + wn * 64 + c16;
#pragma unroll
            for (int nt = 0; nt < 4; ++nt)
                dst[nt * 16] = acc[mt * 4 + nt][r] + bv[nt];
        }
    }
}

// ---- DMA staging with XOR-swizzle via pre-swizzled GLOBAL source (m173/m201)
__device__ __forceinline__ void stage_k(const unsigned short* __restrict__ kb, int kst,
                                        unsigned short* KsX, int w, int lane)
{
#pragma unroll
    for (int i = 0; i < 4; ++i) {
        const int o = (w << 12) + (i << 10) + (lane << 4);   // byte offset in 16KB tile
        const int r = o >> 8;
        const int c = ((o >> 4) & 15) ^ (r & 7);
        gload_lds16(kb + (size_t)r * kst + (c << 3), (char*)KsX + (w << 12) + (i << 10));
    }
}
__device__ __forceinline__ void stage_v(const unsigned short* __restrict__ vb, int vst,
                                        unsigned short* VsX, int w, int lane)
{
#pragma unroll
    for (int i = 0; i < 4; ++i) {
        const int o = (w << 12) + (i << 10) + (lane << 4);
        const int r = o >> 7;
        const int c = ((o >> 4) & 7) ^ (r & 7);
        gload_lds16(vb + (size_t)r * vst + (c << 3), (char*)VsX + (w << 12) + (i << 10));
    }
}

// ============ MFMA flash attention — DMA-staged, swizzled + T13 defer-max ===
// R9: add defer-max (HK THR=8, m214v23/m239): when the tile max doesn't grow
// past m_r+8 for ALL lanes (wave-uniform), keep m_r and skip the 64-mult
// O-rescale; P bounded by e^8 (bf16-safe), l_r/O stay consistent. +5% attn.
__global__ __launch_bounds__(256, 2)
void attn_mfma_kernel(const unsigned short* __restrict__ qb,
                      const unsigned short* __restrict__ Kr,
                      const unsigned short* __restrict__ memb,
                      const unsigned short* __restrict__ Vrt,
                      const unsigned short* __restrict__ memt,
                      unsigned short* __restrict__ attn_h,
                      unsigned short* __restrict__ attn_l)
{
    __shared__ unsigned short lds[40960];     // 81,920 B
    unsigned short* Ks0 = lds;                // 16 KB each
    unsigned short* Ks1 = lds + 8192;
    unsigned short* Vs0 = lds + 16384;
    unsigned short* Vs1 = lds + 24576;
    unsigned short* Ps  = lds + 32768;        // 128 x 64 u16, swizzled
    unsigned short* Os  = lds;                // overlay: Q stage / epilogue (34,816 B)

    const int tid = threadIdx.x;
    const int w = tid >> 6, lane = tid & 63;
    const int c16 = lane & 15, quad = lane >> 4;
    const int bx = blockIdx.x;
    const int h = blockIdx.y, b = blockIdx.z;
    const int qt = b ? bx : (15 - bx);
    const int t0 = qt << 7;               // 128-row q tile
    const int bT = b * T_SEQ;
    const int bh = b * H_NUM + h;

    const unsigned short* Krb = Kr + (size_t)bh * (2048 * 128);
    const unsigned short* Vrb = Vrt + (size_t)bh * (2048 * 128);
    const unsigned short* membh = memb + h * D_HEAD;
    const unsigned short* memth = memt + (size_t)h * D_HEAD * 1024;

    bf16x8 qfrag[2][4];
    {
        const int row = tid >> 1, co = (tid & 1) << 6;
        const unsigned short* src = qb + (size_t)(bT + t0 + row) * 2048 + h * D_HEAD + co;
#pragma unroll
        for (int i = 0; i < 8; ++i)
            *(float4*)&Os[row * 136 + co + (i << 3)] = *(const float4*)(src + (i << 3));
#pragma unroll
        for (int qi = 0; qi < 2; ++qi) {
            const int q = (w << 5) + qi * 16 + c16;
#pragma unroll
            for (int kk = 0; kk < 4; ++kk)
                qfrag[qi][kk] = *(const bf16x8*)&Os[q * 136 + (kk << 5) + (quad << 3)];
        }
    }
    __syncthreads();   // all Q frags read before DMA overwrites the overlay

    f32x4 acc_o[2][8];
#pragma unroll
    for (int qi = 0; qi < 2; ++qi)
#pragma unroll
        for (int i = 0; i < 8; ++i) acc_o[qi][i] = (f32x4){0.f, 0.f, 0.f, 0.f};
    float m_r[2] = {-1e30f, -1e30f};
    float l_r[2] = {0.f, 0.f};

    const int nk = (t0 >> 6) + 2;          // causal s-tiles (64 wide)
    const int ntile = nk + (MEM_N >> 6);

    stage_k(Krb, 128, Ks0, w, lane);
    stage_v(Vrb, 2048, Vs0, w, lane);

    const int sw = c16 & 7;                // read-side XOR key (row & 7)

    for (int it = 0; it < ntile; ++it) {
        __syncthreads();   // drains vmcnt: tile[it] staged; prev compute done

        if (it + 1 < ntile) {
            const int nx = it + 1;
            const bool nm = nx >= nk;
            const int sl = (nm ? nx - nk : nx) << 6;
            const unsigned short* kb = nm ? membh + (size_t)sl * 2048 : Krb + (size_t)sl * 128;
            const unsigned short* vb = nm ? memth + sl : Vrb + sl;
            stage_k(kb, nm ? 2048 : 128, (it & 1) ? Ks0 : Ks1, w, lane);
            stage_v(vb, nm ? 1024 : 2048, (it & 1) ? Vs0 : Vs1, w, lane);
        }

        const unsigned short* Kc = (it & 1) ? Ks1 : Ks0;
        const unsigned short* Vc = (it & 1) ? Vs1 : Vs0;
        const bool mem_t = it >= nk;
        const int sl0 = (mem_t ? it - nk : it) << 6;
        const int s0 = mem_t ? T_SEQ + sl0 : sl0;

        const bool active = mem_t || (s0 <= t0 + (w << 5) + 31);
        if (active) {
            f32x4 acc_s[4][2];
#pragma unroll
            for (int nt = 0; nt < 4; ++nt)
#pragma unroll
                for (int qi = 0; qi < 2; ++qi) acc_s[nt][qi] = (f32x4){0.f, 0.f, 0.f, 0.f};

            bf16x8 ka[4][4];
#pragma unroll
            for (int nt = 0; nt < 4; ++nt) {
                const int rr = nt * 16 + c16;
#pragma unroll
                for (int kk = 0; kk < 4; ++kk)
                    ka[nt][kk] = *(const bf16x8*)&Kc[rr * 128 + ((((kk << 2) + quad) ^ sw) << 3)];
            }
            __builtin_amdgcn_s_setprio(1);
#pragma unroll
            for (int kk = 0; kk < 4; ++kk)
#pragma unroll
                for (int nt = 0; nt < 4; ++nt)
#pragma unroll
                    for (int qi = 0; qi < 2; ++qi)
                        acc_s[nt][qi] = __builtin_amdgcn_mfma_f32_16x16x32_bf16(ka[nt][kk], qfrag[qi][kk], acc_s[nt][qi], 0, 0, 0);
            __builtin_amdgcn_s_setprio(0);

            if (!mem_t && (s0 + 63 > t0 + (w << 5))) {
#pragma unroll
                for (int nt = 0; nt < 4; ++nt) {
                    const int sbase = s0 + nt * 16 + quad * 4;
#pragma unroll
                    for (int qi = 0; qi < 2; ++qi) {
                        const int q = t0 + (w << 5) + qi * 16 + c16;
#pragma unroll
                        for (int r = 0; r < 4; ++r)
                            if (sbase + r > q) acc_s[nt][qi][r] = -1e30f;
                    }
                }
            }

            float mx[2], al[2], rs[2];
#pragma unroll
            for (int qi = 0; qi < 2; ++qi) {
                float m0 = fmaxf(fmaxf(acc_s[0][qi][0], acc_s[0][qi][1]), fmaxf(acc_s[0][qi][2], acc_s[0][qi][3]));
#pragma unroll
                for (int nt = 1; nt < 4; ++nt)
                    m0 = fmaxf(m0, fmaxf(fmaxf(acc_s[nt][qi][0], acc_s[nt][qi][1]), fmaxf(acc_s[nt][qi][2], acc_s[nt][qi][3])));
                m0 = fmaxf(m0, __shfl_xor(m0, 16));
                m0 = fmaxf(m0, __shfl_xor(m0, 32));
                mx[qi] = m0;
            }
            // T13 defer-max: wave-uniform skip of the O-rescale
            const bool defer = __all((mx[0] <= m_r[0] + 8.0f) && (mx[1] <= m_r[1] + 8.0f));
#pragma unroll
            for (int qi = 0; qi < 2; ++qi) {
                const float mn = defer ? m_r[qi] : fmaxf(m_r[qi], mx[qi]);
                al[qi] = defer ? 1.0f : __expf(m_r[qi] - mn);
                m_r[qi] = mn;
                float s = 0.f;
#pragma unroll
                for (int nt = 0; nt < 4; ++nt)
#pragma unroll
                    for (int r = 0; r < 4; ++r) {
                        const float p = __expf(acc_s[nt][qi][r] - mn);
                        acc_s[nt][qi][r] = p;
                        s += p;
                    }
                rs[qi] = s;
            }
#pragma unroll
            for (int qi = 0; qi < 2; ++qi) {
                rs[qi] += __shfl_xor(rs[qi], 16);
                rs[qi] += __shfl_xor(rs[qi], 32);
                l_r[qi] = l_r[qi] * al[qi] + rs[qi];
            }
            if (!defer) {
#pragma unroll
                for (int qi = 0; qi < 2; ++qi)
#pragma unroll
                    for (int dt = 0; dt < 8; ++dt)
#pragma unroll
                        for (int r = 0; r < 4; ++r) acc_o[qi][dt][r] *= al[qi];
            }

#pragma unroll
            for (int qi = 0; qi < 2; ++qi) {
                const int q = (w << 5) + qi * 16 + c16;
                const int qx = (q & 7) << 4;
#pragma unroll
                for (int nt = 0; nt < 4; ++nt) {
                    ushort4 pk;
                    pk.x = f2bf(acc_s[nt][qi][0]); pk.y = f2bf(acc_s[nt][qi][1]);
                    pk.z = f2bf(acc_s[nt][qi][2]); pk.w = f2bf(acc_s[nt][qi][3]);
                    *(ushort4*)((char*)Ps + q * 128 + (((nt << 5) + (quad << 3)) ^ qx)) = pk;
                }
            }

            __builtin_amdgcn_s_setprio(1);
#pragma unroll
            for (int ks = 0; ks < 2; ++ks) {
                bf16x8 pb[2];
#pragma unroll
                for (int qi = 0; qi < 2; ++qi) {
                    const int q = (w << 5) + qi * 16 + c16;
                    pb[qi] = *(const bf16x8*)((char*)Ps + q * 128 + (((ks << 6) + (quad << 4)) ^ ((q & 7) << 4)));
                }
#pragma unroll
                for (int dt = 0; dt < 8; ++dt) {
                    const int rr = dt * 16 + c16;
                    const bf16x8 va = *(const bf16x8*)&Vc[rr * 64 + ((((ks << 2) + quad) ^ sw) << 3)];
                    acc_o[0][dt] = __builtin_amdgcn_mfma_f32_16x16x32_bf16(va, pb[0], acc_o[0][dt], 0, 0, 0);
                    acc_o[1][dt] = __builtin_amdgcn_mfma_f32_16x16x32_bf16(va, pb[1], acc_o[1][dt], 0, 0, 0);
                }
            }
            __builtin_amdgcn_s_setprio(0);
        }
    }

    __syncthreads();   // all compute done; Os overlays the K/V buffers
    const float inv[2] = {1.0f / l_r[0], 1.0f / l_r[1]};
    const int row = tid >> 1, co = (tid & 1) << 6;
    unsigned short* gh = attn_h + (size_t)(bT + t0 + row) * 2048 + h * D_HEAD + co;
    unsigned short* gl = attn_l + (size_t)(bT + t0 + row) * 2048 + h * D_HEAD + co;

#pragma unroll
    for (int pass = 0; pass < 2; ++pass) {
#pragma unroll
        for (int qi = 0; qi < 2; ++qi) {
            const int q = (w << 5) + qi * 16 + c16;
#pragma unroll
            for (int dt = 0; dt < 8; ++dt) {
                ushort4 ov;
                unsigned short* po = (unsigned short*)&ov;
#pragma unroll
                for (int r = 0; r < 4; ++r) {
                    const float o = acc_o[qi][dt][r] * inv[qi];
                    const unsigned int u = __float_as_uint(o);
                    if (pass == 0) {
                        po[r] = (unsigned short)(u >> 16);     // truncated hi
                    } else {
                        const float lo = o - __uint_as_float(u & 0xFFFF0000u);
                        po[r] = f2bf(lo);
                    }
                }
                *(ushort4*)&Os[q * 136 + dt * 16 + quad * 4] = ov;
            }
        }
        unsigned short* g = (pass == 0) ? gh : gl;
#pragma unroll
        for (int i = 0; i < 8; ++i)
            *(float4*)(g + (i << 3)) = *(const float4*)&Os[row * 136 + co + (i << 3)];
    }
}

extern "C" void kernel_launch(void* const* d_in, const int* in_sizes, int n_in,
                              void* d_out, int out_size, void* d_ws, size_t ws_size,
                              hipStream_t stream)
{
    const float* x     = (const float*)d_in[0];
    const float* Wqkv  = (const float*)d_in[1];
    const float* bqkv  = (const float*)d_in[2];
    const float* mem   = (const float*)d_in[3];
    const float* Wproj = (const float*)d_in[4];
    const float* bproj = (const float*)d_in[5];
    float* out = (float*)d_out;

    unsigned short* ws16 = (unsigned short*)d_ws;
    unsigned short* WqTh = ws16;                         // 12,582,912
    unsigned short* rgn2 = WqTh + 12582912;              // 12,582,912
    unsigned short* qb   = rgn2 + 12582912;              //  8,388,608
    unsigned short* Kr   = qb   + 8388608;               //  8,388,608
    unsigned short* Vr   = Kr   + 8388608;               //  8,388,608
    unsigned short* Vrt  = Vr   + 8388608;               //  8,388,608
    unsigned short* memb = Vrt  + 8388608;               //  2,097,152
    unsigned short* memt = memb + 2097152;               //  2,097,152
    unsigned short* attn_h = WqTh;                       // overlay (WqTh dead after gemm1)
    unsigned short* attn_l = rgn2;
    unsigned short* WpTh = rgn2 + 8388608;               //  4,194,304 tail
    unsigned short* Axh = rgn2;                          // dead before attn_l is written
    unsigned short* Axl = Vrt;                           // dead before transpose_v writes Vrt

    prep_kernel<<<dim3(8704), 256, 0, stream>>>(x, Axh, Axl, Wqkv, WqTh,
                                                Wproj, WpTh, mem, memb, memt);

    gemm_qkv_mfma<<<dim3(24, 32), 256, 0, stream>>>(Axh, Axl, WqTh, bqkv, qb, Kr, Vr);

    transpose_v_kernel<<<dim3(32, 16, 2), 256, 0, stream>>>(Vr, Vrt);

    attn_mfma_kernel<<<dim3(16, 16, 2), 256, 0, stream>>>(qb, Kr, memb, Vrt, memt, attn_h, attn_l);

    gemm_proj_mfma<<<dim3(16, 32), 256, 0, stream>>>(attn_h, attn_l, WpTh, bproj, out);
}